// Round 6
// baseline (82.719 us; speedup 1.0000x reference)
//
#include <hip/hip_runtime.h>
#include <hip/hip_bf16.h>

// Problem constants (B,T,H,D,M) = (2, 2048, 8, 64, 64), fp32 in/out.
#define BB 2
#define TT 2048
#define HH 8
#define DD 64
#define CC 256           // chunks over T
#define TC (TT / CC)     // 8 timesteps per chunk (= 4 segs x 2 iters)
#define STRIDE (HH * DD) // 512 floats between consecutive timesteps
#define NBH (BB * HH)    // 16
#define NSPAN 16         // spans per (b,h); 16 chunks per span
#define NCHUNK (NBH * CC)

__device__ __forceinline__ float feat(float x) {
    // elu(x) + 1 = x+1 (x>0) else exp(x)
    return x > 0.f ? x + 1.f : __expf(x);
}

// Lane map: g = lane&15 -> d-group (d = 4g..4g+3), seg = lane>>4 -> timestep
// within group-of-4. One wave float4-load = 4 timesteps x 64 d = 1 KB.

// Kernel 1: hierarchical chunk-sum scan.
// grid = NBH*NSPAN = 256 blocks x 1024 threads; block = (bh, span); wave w
// handles chunk c = span*16 + w. Writes:
//   wse[idx*DD ..] : exclusive prefix of chunk sums WITHIN the span (per d)
//   wst[(bh*16+span)*DD ..] : span total (per d)
__global__ void __launch_bounds__(1024)
chunkscan_kernel(const float* __restrict__ k, float* __restrict__ wse,
                 float* __restrict__ wst) {
    const int bh   = blockIdx.x >> 4;
    const int span = blockIdx.x & (NSPAN - 1);
    const int tid  = threadIdx.x;
    const int w    = tid >> 6;                // wave = chunk-within-span
    const int lane = tid & 63;
    const int g    = lane & 15;
    const int seg  = lane >> 4;

    const int c   = span * NSPAN + w;
    const int idx = bh * CC + c;
    const int h   = bh & (HH - 1);
    const int b   = bh >> 3;

    const size_t off0 = (((size_t)b * TT + c * TC + seg) * HH + h) * DD + g * 4;
    const float4 k0 = *(const float4*)(k + off0);
    const float4 k1 = *(const float4*)(k + off0 + (size_t)4 * STRIDE);

    float4 s;
    s.x = feat(k0.x) + feat(k1.x);
    s.y = feat(k0.y) + feat(k1.y);
    s.z = feat(k0.z) + feat(k1.z);
    s.w = feat(k0.w) + feat(k1.w);

    // reduce over the 4 segments -> all lanes hold the full chunk sum per d-group
    s.x += __shfl_xor(s.x, 16, 64); s.y += __shfl_xor(s.y, 16, 64);
    s.z += __shfl_xor(s.z, 16, 64); s.w += __shfl_xor(s.w, 16, 64);
    s.x += __shfl_xor(s.x, 32, 64); s.y += __shfl_xor(s.y, 32, 64);
    s.z += __shfl_xor(s.z, 32, 64); s.w += __shfl_xor(s.w, 32, 64);

    __shared__ float tot[NSPAN][DD];
    if (seg == 0) *(float4*)&tot[w][g * 4] = s;
    __syncthreads();

    float4 carry = make_float4(0.f, 0.f, 0.f, 0.f);
    for (int w2 = 0; w2 < w; ++w2) {            // wave-uniform trip count
        const float4 t = *(const float4*)&tot[w2][g * 4];
        carry.x += t.x; carry.y += t.y; carry.z += t.z; carry.w += t.w;
    }

    if (seg == 0) {
        *(float4*)(wse + (size_t)idx * DD + g * 4) = carry;
        if (w == NSPAN - 1) {
            float4 t;
            t.x = carry.x + s.x; t.y = carry.y + s.y;
            t.z = carry.z + s.z; t.w = carry.w + s.w;
            *(float4*)(wst + (size_t)(bh * NSPAN + span) * DD + g * 4) = t;
        }
    }
}

// Kernel 2: main. One wave per (b,h,c) chunk, float4 lane map.
__global__ void __launch_bounds__(64)
linattn_kernel(const float* __restrict__ q, const float* __restrict__ k,
               const float* __restrict__ v, const float* __restrict__ wse,
               const float* __restrict__ wst, float* __restrict__ out) {
    const int idx  = blockIdx.x;
    const int c    = idx & (CC - 1);
    const int bh   = idx >> 8;
    const int h    = bh & (HH - 1);
    const int b    = bh >> 3;
    const int lane = threadIdx.x;
    const int g    = lane & 15;
    const int seg  = lane >> 4;

    // lane's timesteps: t0 = c*TC + seg (iter 0), t0+4 (iter 1); d = 4g..4g+3
    const size_t off0 = (((size_t)b * TT + c * TC + seg) * HH + h) * DD + g * 4;
    const size_t off1 = off0 + (size_t)4 * STRIDE;

    float4 kf0 = *(const float4*)(k + off0);
    float4 kf1 = *(const float4*)(k + off1);
    float4 qf0 = *(const float4*)(q + off0);
    float4 qf1 = *(const float4*)(q + off1);
    const float4 vv0 = *(const float4*)(v + off0);
    const float4 vv1 = *(const float4*)(v + off1);

    // Global exclusive prefix per d: intra-span part + preceding span totals.
    float4 carry = *(const float4*)(wse + (size_t)idx * DD + g * 4);
    {
        const int span = c >> 4;                       // wave-uniform
        const float* wp = wst + (size_t)(bh * NSPAN) * DD + g * 4;
        for (int s2 = 0; s2 < span; ++s2) {
            const float4 t = *(const float4*)(wp + (size_t)s2 * DD);
            carry.x += t.x; carry.y += t.y; carry.z += t.z; carry.w += t.w;
        }
    }

    kf0.x = feat(kf0.x); kf0.y = feat(kf0.y); kf0.z = feat(kf0.z); kf0.w = feat(kf0.w);
    kf1.x = feat(kf1.x); kf1.y = feat(kf1.y); kf1.z = feat(kf1.z); kf1.w = feat(kf1.w);
    qf0.x = feat(qf0.x); qf0.y = feat(qf0.y); qf0.z = feat(qf0.z); qf0.w = feat(qf0.w);
    qf1.x = feat(qf1.x); qf1.y = feat(qf1.y); qf1.z = feat(qf1.z); qf1.w = feat(qf1.w);

    // ---- time cumsum per d: seg-inclusive scans of kf0/kf1 (Hillis-Steele o=16,32)
    float4 i0 = kf0, i1 = kf1;
    {
        float u;
        u = __shfl_up(i0.x, 16, 64); if (seg >= 1) i0.x += u;
        u = __shfl_up(i0.y, 16, 64); if (seg >= 1) i0.y += u;
        u = __shfl_up(i0.z, 16, 64); if (seg >= 1) i0.z += u;
        u = __shfl_up(i0.w, 16, 64); if (seg >= 1) i0.w += u;
        u = __shfl_up(i1.x, 16, 64); if (seg >= 1) i1.x += u;
        u = __shfl_up(i1.y, 16, 64); if (seg >= 1) i1.y += u;
        u = __shfl_up(i1.z, 16, 64); if (seg >= 1) i1.z += u;
        u = __shfl_up(i1.w, 16, 64); if (seg >= 1) i1.w += u;
        u = __shfl_up(i0.x, 32, 64); if (seg >= 2) i0.x += u;
        u = __shfl_up(i0.y, 32, 64); if (seg >= 2) i0.y += u;
        u = __shfl_up(i0.z, 32, 64); if (seg >= 2) i0.z += u;
        u = __shfl_up(i0.w, 32, 64); if (seg >= 2) i0.w += u;
        u = __shfl_up(i1.x, 32, 64); if (seg >= 2) i1.x += u;
        u = __shfl_up(i1.y, 32, 64); if (seg >= 2) i1.y += u;
        u = __shfl_up(i1.z, 32, 64); if (seg >= 2) i1.z += u;
        u = __shfl_up(i1.w, 32, 64); if (seg >= 2) i1.w += u;
    }
    // S0[d] = first-half chunk total = i0 at seg=3 (lane 48+g), broadcast
    float4 S0;
    S0.x = __shfl(i0.x, 48 + g, 64);
    S0.y = __shfl(i0.y, 48 + g, 64);
    S0.z = __shfl(i0.z, 48 + g, 64);
    S0.w = __shfl(i0.w, 48 + g, 64);

    float4 run0, run1;   // inclusive time-cumsum of feat(k) per d
    run0.x = carry.x + i0.x; run0.y = carry.y + i0.y;
    run0.z = carry.z + i0.z; run0.w = carry.w + i0.w;
    run1.x = carry.x + S0.x + i1.x; run1.y = carry.y + S0.y + i1.y;
    run1.z = carry.z + S0.z + i1.z; run1.w = carry.w + S0.w + i1.w;

    // ---- d-prefix (inclusive over d) per timestep: in-lane prefix + group scan
    float4 p0, p1;
    p0.x = kf0.x; p0.y = p0.x + kf0.y; p0.z = p0.y + kf0.z; p0.w = p0.z + kf0.w;
    p1.x = kf1.x; p1.y = p1.x + kf1.y; p1.z = p1.y + kf1.z; p1.w = p1.z + kf1.w;
    float c0 = p0.w, c1 = p1.w;
    #pragma unroll
    for (int o = 1; o <= 8; o <<= 1) {
        float u0 = __shfl_up(c0, o, 16);
        float u1 = __shfl_up(c1, o, 16);
        if (g >= o) { c0 += u0; c1 += u1; }
    }
    const float e0 = c0 - p0.w;   // exclusive d-prefix entering this lane
    const float e1 = c1 - p1.w;
    float4 pre0, pre1;
    pre0.x = p0.x + e0; pre0.y = p0.y + e0; pre0.z = p0.z + e0; pre0.w = p0.w + e0;
    pre1.x = p1.x + e1; pre1.y = p1.y + e1; pre1.z = p1.z + e1; pre1.w = p1.w + e1;

    // ---- reductions over d: s1 = qf.pre, s2 = qf.run (per timestep = per segment)
    float s1_0 = qf0.x * pre0.x + qf0.y * pre0.y + qf0.z * pre0.z + qf0.w * pre0.w;
    float s2_0 = qf0.x * run0.x + qf0.y * run0.y + qf0.z * run0.z + qf0.w * run0.w;
    float s1_1 = qf1.x * pre1.x + qf1.y * pre1.y + qf1.z * pre1.z + qf1.w * pre1.w;
    float s2_1 = qf1.x * run1.x + qf1.y * run1.y + qf1.z * run1.z + qf1.w * run1.w;
    #pragma unroll
    for (int o = 1; o <= 8; o <<= 1) {
        s1_0 += __shfl_xor(s1_0, o, 64);
        s2_0 += __shfl_xor(s2_0, o, 64);
        s1_1 += __shfl_xor(s1_1, o, 64);
        s2_1 += __shfl_xor(s2_1, o, 64);
    }

    const float r0 = s1_0 * __builtin_amdgcn_rcpf(s2_0);
    const float r1 = s1_1 * __builtin_amdgcn_rcpf(s2_1);
    float4 o0, o1;
    o0.x = vv0.x * r0; o0.y = vv0.y * r0; o0.z = vv0.z * r0; o0.w = vv0.w * r0;
    o1.x = vv1.x * r1; o1.y = vv1.y * r1; o1.z = vv1.z * r1; o1.w = vv1.w * r1;
    *(float4*)(out + off0) = o0;
    *(float4*)(out + off1) = o1;
}

extern "C" void kernel_launch(void* const* d_in, const int* in_sizes, int n_in,
                              void* d_out, int out_size, void* d_ws, size_t ws_size,
                              hipStream_t stream) {
    const float* q = (const float*)d_in[0];
    const float* k = (const float*)d_in[1];
    const float* v = (const float*)d_in[2];
    float* out = (float*)d_out;
    float* wse = (float*)d_ws;                         // NCHUNK*DD floats = 1 MB
    float* wst = wse + (size_t)NCHUNK * DD;            // NBH*NSPAN*DD = 64 KB

    chunkscan_kernel<<<NBH * NSPAN, 1024, 0, stream>>>(k, wse, wst);
    linattn_kernel<<<NCHUNK, 64, 0, stream>>>(q, k, v, wse, wst, out);
}

// Round 7
// 79.251 us; speedup vs baseline: 1.0438x; 1.0438x over previous
//
#include <hip/hip_runtime.h>
#include <hip/hip_bf16.h>

// Problem constants (B,T,H,D,M) = (2, 2048, 8, 64, 64), fp32 in/out.
#define BB 2
#define TT 2048
#define HH 8
#define DD 64
#define CC 256           // chunks over T
#define TC (TT / CC)     // 8 timesteps per chunk (= 4 segs x 2 iters)
#define STRIDE (HH * DD) // 512 floats between consecutive timesteps
#define NBH (BB * HH)    // 16
#define PW (CC / 16)     // 16 chunks per wave in prefix_kernel

__device__ __forceinline__ float feat(float x) {
    // elu(x) + 1 = x+1 (x>0) else exp(x)
    return x > 0.f ? x + 1.f : __expf(x);
}

// Lane map for K1/K3: g = lane&15 -> d-group (d = 4g..4g+3), seg = lane>>4 ->
// timestep within group-of-4. One wave float4-load = 4 timesteps x 64 d = 1 KB.

// Kernel 1: per (b,h,c) chunk sums of feat(k) over time. wave per chunk.
__global__ void __launch_bounds__(64)
chunk_sums_kernel(const float* __restrict__ k, float* __restrict__ ws) {
    const int idx  = blockIdx.x;              // (b*H + h)*CC + c
    const int c    = idx & (CC - 1);
    const int h    = (idx >> 8) & (HH - 1);
    const int b    = idx >> 11;
    const int lane = threadIdx.x;
    const int g    = lane & 15;
    const int seg  = lane >> 4;

    const size_t off0 = (((size_t)b * TT + c * TC + seg) * HH + h) * DD + g * 4;
    const float4 k0 = *(const float4*)(k + off0);
    const float4 k1 = *(const float4*)(k + off0 + (size_t)4 * STRIDE);

    float4 s;
    s.x = feat(k0.x) + feat(k1.x);
    s.y = feat(k0.y) + feat(k1.y);
    s.z = feat(k0.z) + feat(k1.z);
    s.w = feat(k0.w) + feat(k1.w);

    // reduce over the 4 segments (lanes ^16, ^32)
    s.x += __shfl_xor(s.x, 16, 64); s.y += __shfl_xor(s.y, 16, 64);
    s.z += __shfl_xor(s.z, 16, 64); s.w += __shfl_xor(s.w, 16, 64);
    s.x += __shfl_xor(s.x, 32, 64); s.y += __shfl_xor(s.y, 32, 64);
    s.z += __shfl_xor(s.z, 32, 64); s.w += __shfl_xor(s.w, 32, 64);

    if (seg == 0)
        *(float4*)(ws + (size_t)idx * DD + g * 4) = s;
}

// Kernel 2 (verified round-3): in-place ws chunk sums -> EXCLUSIVE prefix over c.
__global__ void __launch_bounds__(1024)
prefix_kernel(float* __restrict__ ws) {
    const int bh   = blockIdx.x;              // 0..15
    const int lane = threadIdx.x & 63;        // d
    const int w    = threadIdx.x >> 6;        // wave id 0..15

    size_t base = ((size_t)bh * CC + w * PW) * DD + lane;

    float val[PW];
    #pragma unroll
    for (int i = 0; i < PW; ++i) val[i] = ws[base + (size_t)i * DD];

    float run = 0.f, excl[PW];
    #pragma unroll
    for (int i = 0; i < PW; ++i) { excl[i] = run; run += val[i]; }

    __shared__ float tot[16][DD];
    tot[w][lane] = run;
    __syncthreads();

    float carry = 0.f;
    for (int w2 = 0; w2 < w; ++w2) carry += tot[w2][lane];

    #pragma unroll
    for (int i = 0; i < PW; ++i) ws[base + (size_t)i * DD] = excl[i] + carry;
}

// Kernel 3: main. One wave per (b,h,c) chunk, float4 lane map.
__global__ void __launch_bounds__(64)
linattn_kernel(const float* __restrict__ q, const float* __restrict__ k,
               const float* __restrict__ v, const float* __restrict__ ws,
               float* __restrict__ out) {
    const int idx  = blockIdx.x;
    const int c    = idx & (CC - 1);
    const int h    = (idx >> 8) & (HH - 1);
    const int b    = idx >> 11;
    const int lane = threadIdx.x;
    const int g    = lane & 15;
    const int seg  = lane >> 4;

    // lane's timesteps: t0 = c*TC + seg (iter 0), t0+4 (iter 1); d = 4g..4g+3
    const size_t off0 = (((size_t)b * TT + c * TC + seg) * HH + h) * DD + g * 4;
    const size_t off1 = off0 + (size_t)4 * STRIDE;

    float4 kf0 = *(const float4*)(k + off0);
    float4 kf1 = *(const float4*)(k + off1);
    float4 qf0 = *(const float4*)(q + off0);
    float4 qf1 = *(const float4*)(q + off1);
    const float4 vv0 = *(const float4*)(v + off0);
    const float4 vv1 = *(const float4*)(v + off1);
    const float4 carry = *(const float4*)(ws + (size_t)idx * DD + g * 4); // excl prefix per d

    kf0.x = feat(kf0.x); kf0.y = feat(kf0.y); kf0.z = feat(kf0.z); kf0.w = feat(kf0.w);
    kf1.x = feat(kf1.x); kf1.y = feat(kf1.y); kf1.z = feat(kf1.z); kf1.w = feat(kf1.w);
    qf0.x = feat(qf0.x); qf0.y = feat(qf0.y); qf0.z = feat(qf0.z); qf0.w = feat(qf0.w);
    qf1.x = feat(qf1.x); qf1.y = feat(qf1.y); qf1.z = feat(qf1.z); qf1.w = feat(qf1.w);

    // ---- time cumsum per d: seg-inclusive scans of kf0/kf1 (Hillis-Steele o=16,32)
    float4 i0 = kf0, i1 = kf1;
    {
        float u;
        u = __shfl_up(i0.x, 16, 64); if (seg >= 1) i0.x += u;
        u = __shfl_up(i0.y, 16, 64); if (seg >= 1) i0.y += u;
        u = __shfl_up(i0.z, 16, 64); if (seg >= 1) i0.z += u;
        u = __shfl_up(i0.w, 16, 64); if (seg >= 1) i0.w += u;
        u = __shfl_up(i1.x, 16, 64); if (seg >= 1) i1.x += u;
        u = __shfl_up(i1.y, 16, 64); if (seg >= 1) i1.y += u;
        u = __shfl_up(i1.z, 16, 64); if (seg >= 1) i1.z += u;
        u = __shfl_up(i1.w, 16, 64); if (seg >= 1) i1.w += u;
        u = __shfl_up(i0.x, 32, 64); if (seg >= 2) i0.x += u;
        u = __shfl_up(i0.y, 32, 64); if (seg >= 2) i0.y += u;
        u = __shfl_up(i0.z, 32, 64); if (seg >= 2) i0.z += u;
        u = __shfl_up(i0.w, 32, 64); if (seg >= 2) i0.w += u;
        u = __shfl_up(i1.x, 32, 64); if (seg >= 2) i1.x += u;
        u = __shfl_up(i1.y, 32, 64); if (seg >= 2) i1.y += u;
        u = __shfl_up(i1.z, 32, 64); if (seg >= 2) i1.z += u;
        u = __shfl_up(i1.w, 32, 64); if (seg >= 2) i1.w += u;
    }
    // S0[d] = chunk-first-half total = i0 at seg=3 (lane 48+g), broadcast
    float4 S0;
    S0.x = __shfl(i0.x, 48 + g, 64);
    S0.y = __shfl(i0.y, 48 + g, 64);
    S0.z = __shfl(i0.z, 48 + g, 64);
    S0.w = __shfl(i0.w, 48 + g, 64);

    float4 run0, run1;   // inclusive time-cumsum of feat(k) per d
    run0.x = carry.x + i0.x; run0.y = carry.y + i0.y;
    run0.z = carry.z + i0.z; run0.w = carry.w + i0.w;
    run1.x = carry.x + S0.x + i1.x; run1.y = carry.y + S0.y + i1.y;
    run1.z = carry.z + S0.z + i1.z; run1.w = carry.w + S0.w + i1.w;

    // ---- d-prefix (inclusive over d) per timestep: in-lane prefix + group scan
    float4 p0, p1;
    p0.x = kf0.x; p0.y = p0.x + kf0.y; p0.z = p0.y + kf0.z; p0.w = p0.z + kf0.w;
    p1.x = kf1.x; p1.y = p1.x + kf1.y; p1.z = p1.y + kf1.z; p1.w = p1.z + kf1.w;
    float c0 = p0.w, c1 = p1.w;
    #pragma unroll
    for (int o = 1; o <= 8; o <<= 1) {
        float u0 = __shfl_up(c0, o, 16);
        float u1 = __shfl_up(c1, o, 16);
        if (g >= o) { c0 += u0; c1 += u1; }
    }
    const float e0 = c0 - p0.w;   // exclusive d-prefix entering this lane
    const float e1 = c1 - p1.w;
    float4 pre0, pre1;
    pre0.x = p0.x + e0; pre0.y = p0.y + e0; pre0.z = p0.z + e0; pre0.w = p0.w + e0;
    pre1.x = p1.x + e1; pre1.y = p1.y + e1; pre1.z = p1.z + e1; pre1.w = p1.w + e1;

    // ---- reductions over d: s1 = qf.pre, s2 = qf.run (per timestep = per segment)
    float s1_0 = qf0.x * pre0.x + qf0.y * pre0.y + qf0.z * pre0.z + qf0.w * pre0.w;
    float s2_0 = qf0.x * run0.x + qf0.y * run0.y + qf0.z * run0.z + qf0.w * run0.w;
    float s1_1 = qf1.x * pre1.x + qf1.y * pre1.y + qf1.z * pre1.z + qf1.w * pre1.w;
    float s2_1 = qf1.x * run1.x + qf1.y * run1.y + qf1.z * run1.z + qf1.w * run1.w;
    #pragma unroll
    for (int o = 1; o <= 8; o <<= 1) {
        s1_0 += __shfl_xor(s1_0, o, 64);
        s2_0 += __shfl_xor(s2_0, o, 64);
        s1_1 += __shfl_xor(s1_1, o, 64);
        s2_1 += __shfl_xor(s2_1, o, 64);
    }

    const float r0 = s1_0 * __builtin_amdgcn_rcpf(s2_0);
    const float r1 = s1_1 * __builtin_amdgcn_rcpf(s2_1);
    float4 o0, o1;
    o0.x = vv0.x * r0; o0.y = vv0.y * r0; o0.z = vv0.z * r0; o0.w = vv0.w * r0;
    o1.x = vv1.x * r1; o1.y = vv1.y * r1; o1.z = vv1.z * r1; o1.w = vv1.w * r1;
    *(float4*)(out + off0) = o0;
    *(float4*)(out + off1) = o1;
}

extern "C" void kernel_launch(void* const* d_in, const int* in_sizes, int n_in,
                              void* d_out, int out_size, void* d_ws, size_t ws_size,
                              hipStream_t stream) {
    const float* q = (const float*)d_in[0];
    const float* k = (const float*)d_in[1];
    const float* v = (const float*)d_in[2];
    float* out = (float*)d_out;
    float* ws  = (float*)d_ws;            // needs B*H*CC*DD*4 = 1 MB

    const int nblk = BB * HH * CC;        // 4096
    chunk_sums_kernel<<<nblk, 64, 0, stream>>>(k, ws);
    prefix_kernel<<<NBH, 1024, 0, stream>>>(ws);
    linattn_kernel<<<nblk, 64, 0, stream>>>(q, k, v, ws, out);
}